// Round 1
// baseline (712.186 us; speedup 1.0000x reference)
//
#include <hip/hip_runtime.h>

// TemporalKplanesEncoding: out[p, :] = sum_{k=0..2} bilinear(plane_k, inp[p,k], inp[p,3])
// planes: [F=32, H=128, W=256] f32.  N = 2097152 points.
//
// Strategy:
//  1) transpose planes [F,H,W] -> [H,W,F] in a __device__ global (12 MB) so each
//     texel's 32 features are one contiguous 128 B cache line.
//  2) sample kernel: 8 lanes per point; lane f4 owns features [4*f4 .. 4*f4+3].
//     4 corner float4 gathers per plane (full line utilization), coalesced
//     float4 output store (wave writes one contiguous 4 KB chunk).

#define NPTS 2097152
#define FEAT 32
#define PW 256
#define PH 128
#define PLANE_ELEMS (FEAT * PH * PW) // 1048576 floats = 4 MB

__device__ float g_tr[3 * PLANE_ELEMS]; // transposed planes, [k][H][W][F]

__global__ __launch_bounds__(256) void transpose_kernel(
    const float* __restrict__ p0,
    const float* __restrict__ p1,
    const float* __restrict__ p2) {
    int idx = blockIdx.x * 256 + threadIdx.x; // output-linear: [k][t][f]
    int k = idx >> 20;
    int r = idx & (PLANE_ELEMS - 1);
    int t = r >> 5;   // texel id = y*W + x
    int f = r & 31;   // feature
    const float* src = (k == 0) ? p0 : (k == 1) ? p1 : p2;
    // src layout [F, H*W]; reads hit L1 (each 128B line reused by 32 texels).
    g_tr[idx] = src[f * (PH * PW) + t];
}

__global__ __launch_bounds__(256) void sample_kernel(
    const float* __restrict__ inp,
    float* __restrict__ out) {
    int tid = blockIdx.x * 256 + threadIdx.x;
    int p  = tid >> 3; // point index
    int f4 = tid & 7;  // float4 slot within the 32 features

    // all 8 lanes of a point load the same 16B -> broadcast, L1-friendly
    float4 c = reinterpret_cast<const float4*>(inp)[p];
    float cs0 = c.x, cs1 = c.y, cs2 = c.z;

    // y (time) axis shared by all three planes: H = 128
    float y = fminf(fmaxf((c.w + 1.0f) * 63.5f, 0.0f), 127.0f);
    float y0f = floorf(y);
    float wy = y - y0f;
    int y0 = (int)y0f;
    int y1 = min(y0 + 1, PH - 1);
    float omy = 1.0f - wy;
    int r0 = y0 * PW;
    int r1 = y1 * PW;

    float4 acc = make_float4(0.0f, 0.0f, 0.0f, 0.0f);

    const float cxs[3] = {cs0, cs1, cs2};
#pragma unroll
    for (int k = 0; k < 3; ++k) {
        float x = fminf(fmaxf((cxs[k] + 1.0f) * 127.5f, 0.0f), 255.0f);
        float x0f = floorf(x);
        float wx = x - x0f;
        int x0 = (int)x0f;
        int x1 = min(x0 + 1, PW - 1);
        float omx = 1.0f - wx;

        float w00 = omx * omy;
        float w01 = wx * omy;
        float w10 = omx * wy;
        float w11 = wx * wy;

        const float* tp = g_tr + k * PLANE_ELEMS;
        const float4* t00 = (const float4*)(tp + ((r0 + x0) << 5)) + f4;
        const float4* t01 = (const float4*)(tp + ((r0 + x1) << 5)) + f4;
        const float4* t10 = (const float4*)(tp + ((r1 + x0) << 5)) + f4;
        const float4* t11 = (const float4*)(tp + ((r1 + x1) << 5)) + f4;
        float4 v00 = *t00;
        float4 v01 = *t01;
        float4 v10 = *t10;
        float4 v11 = *t11;

        acc.x += v00.x * w00 + v01.x * w01 + v10.x * w10 + v11.x * w11;
        acc.y += v00.y * w00 + v01.y * w01 + v10.y * w10 + v11.y * w11;
        acc.z += v00.z * w00 + v01.z * w01 + v10.z * w10 + v11.z * w11;
        acc.w += v00.w * w00 + v01.w * w01 + v10.w * w10 + v11.w * w11;
    }

    // out[p*32 + 4*f4 .. +3] ; tid-linear -> fully coalesced
    reinterpret_cast<float4*>(out)[tid] = acc;
}

extern "C" void kernel_launch(void* const* d_in, const int* in_sizes, int n_in,
                              void* d_out, int out_size, void* d_ws, size_t ws_size,
                              hipStream_t stream) {
    const float* inp = (const float*)d_in[0];
    const float* p0 = (const float*)d_in[1];
    const float* p1 = (const float*)d_in[2];
    const float* p2 = (const float*)d_in[3];
    float* out = (float*)d_out;

    transpose_kernel<<<(3 * PLANE_ELEMS) / 256, 256, 0, stream>>>(p0, p1, p2);
    sample_kernel<<<(NPTS * 8) / 256, 256, 0, stream>>>(inp, out);
}

// Round 2
// 489.959 us; speedup vs baseline: 1.4536x; 1.4536x over previous
//
#include <hip/hip_runtime.h>

// TemporalKplanesEncoding: out[p, :] = sum_{k=0..2} bilinear(plane_k, inp[p,k], inp[p,3])
// planes: [F=32, H=128, W=256] f32.  N = 2097152 points.
//
// R2 strategy: all 3 planes share the t axis (row index). Bucket points by
// t-row (128 bins) into workspace, then sample bin-by-bin so the active
// working set is 3 planes x 2 rows = 192 KB -> L2-resident. R1's random-order
// gathers caused 1.64 GB of L2-miss fetch; binning makes gathers L2 hits.

#define NPTS 2097152
#define FEAT 32
#define PW 256
#define PH 128
#define PLANE_ELEMS (FEAT * PH * PW) // 4 MB per plane
#define NBINS 128
#define BIN_CAP 24576                 // mean 16384/bin, ~64 sigma headroom
#define BLOCKS_PER_BIN (BIN_CAP / 32) // 768 sample blocks per bin (32 pts each)

__device__ float g_tr[3 * PLANE_ELEMS]; // transposed planes, [k][H][W][F]

__global__ __launch_bounds__(256) void transpose_kernel(
    const float* __restrict__ p0,
    const float* __restrict__ p1,
    const float* __restrict__ p2) {
    int idx = blockIdx.x * 256 + threadIdx.x; // output-linear: [k][t][f]
    int k = idx >> 20;
    int r = idx & (PLANE_ELEMS - 1);
    int t = r >> 5;   // texel id = y*W + x
    int f = r & 31;   // feature
    const float* src = (k == 0) ? p0 : (k == 1) ? p1 : p2;
    g_tr[idx] = src[f * (PH * PW) + t];
}

__global__ __launch_bounds__(128) void zero_counts_kernel(int* counts) {
    counts[threadIdx.x] = 0;
}

// 256 blocks x 1024 threads x 8 points: LDS-aggregated counting scatter by t-row.
__global__ __launch_bounds__(1024) void scatter_kernel(
    const float* __restrict__ inp,
    float4* __restrict__ s_coords,
    int* __restrict__ s_ids,
    int* __restrict__ counts) {
    __shared__ int hist[NBINS];
    __shared__ int base[NBINS];
    int tid = threadIdx.x;
    if (tid < NBINS) hist[tid] = 0;
    __syncthreads();

    float4 c[8];
    int tag[8];
    int p0 = blockIdx.x * 8192 + tid;
#pragma unroll
    for (int i = 0; i < 8; ++i) {
        c[i] = reinterpret_cast<const float4*>(inp)[p0 + i * 1024];
        float y = fminf(fmaxf((c[i].w + 1.0f) * 63.5f, 0.0f), 127.0f);
        int bin = (int)floorf(y); // 0..127
        int lpos = atomicAdd(&hist[bin], 1); // block-local, <= 8192
        tag[i] = (bin << 16) | lpos;
    }
    __syncthreads();
    if (tid < NBINS) base[tid] = atomicAdd(&counts[tid], hist[tid]);
    __syncthreads();
#pragma unroll
    for (int i = 0; i < 8; ++i) {
        int bin = tag[i] >> 16;
        int pos = base[bin] + (tag[i] & 0xffff);
        int idx = bin * BIN_CAP + pos;
        s_coords[idx] = c[i];
        s_ids[idx] = p0 + i * 1024;
    }
}

__device__ __forceinline__ float4 bilinear_sum(float4 c, int f4) {
    float y = fminf(fmaxf((c.w + 1.0f) * 63.5f, 0.0f), 127.0f);
    float y0f = floorf(y);
    float wy = y - y0f;
    int y0 = (int)y0f;
    int y1 = min(y0 + 1, PH - 1);
    float omy = 1.0f - wy;
    int r0 = y0 * PW;
    int r1 = y1 * PW;

    float4 acc = make_float4(0.0f, 0.0f, 0.0f, 0.0f);
    const float cxs[3] = {c.x, c.y, c.z};
#pragma unroll
    for (int k = 0; k < 3; ++k) {
        float x = fminf(fmaxf((cxs[k] + 1.0f) * 127.5f, 0.0f), 255.0f);
        float x0f = floorf(x);
        float wx = x - x0f;
        int x0 = (int)x0f;
        int x1 = min(x0 + 1, PW - 1);
        float omx = 1.0f - wx;

        float w00 = omx * omy;
        float w01 = wx * omy;
        float w10 = omx * wy;
        float w11 = wx * wy;

        const float* tp = g_tr + k * PLANE_ELEMS;
        float4 v00 = *((const float4*)(tp + ((r0 + x0) << 5)) + f4);
        float4 v01 = *((const float4*)(tp + ((r0 + x1) << 5)) + f4);
        float4 v10 = *((const float4*)(tp + ((r1 + x0) << 5)) + f4);
        float4 v11 = *((const float4*)(tp + ((r1 + x1) << 5)) + f4);

        acc.x += v00.x * w00 + v01.x * w01 + v10.x * w10 + v11.x * w11;
        acc.y += v00.y * w00 + v01.y * w01 + v10.y * w10 + v11.y * w11;
        acc.z += v00.z * w00 + v01.z * w01 + v10.z * w10 + v11.z * w11;
        acc.w += v00.w * w00 + v01.w * w01 + v10.w * w10 + v11.w * w11;
    }
    return acc;
}

// grid (BLOCKS_PER_BIN, NBINS); 256 threads = 32 points x 8 feature-lanes.
// Consecutive blocks share a bin -> 192 KB active working set -> L2 hits.
__global__ __launch_bounds__(256) void sample_sorted_kernel(
    const float4* __restrict__ s_coords,
    const int* __restrict__ s_ids,
    const int* __restrict__ counts,
    float* __restrict__ out) {
    int bin = blockIdx.y;
    int slot = blockIdx.x * 32 + (threadIdx.x >> 3);
    if (slot >= counts[bin]) return;
    int f4 = threadIdx.x & 7;
    int idx = bin * BIN_CAP + slot;
    float4 c = s_coords[idx]; // 8 lanes broadcast-load same 16B
    int id = s_ids[idx];

    float4 acc = bilinear_sum(c, f4);
    reinterpret_cast<float4*>(out)[id * 8 + f4] = acc; // full 128B line per point
}

// R1 fallback path (unsorted), used when ws is too small.
__global__ __launch_bounds__(256) void sample_kernel(
    const float* __restrict__ inp,
    float* __restrict__ out) {
    int tid = blockIdx.x * 256 + threadIdx.x;
    int p  = tid >> 3;
    int f4 = tid & 7;
    float4 c = reinterpret_cast<const float4*>(inp)[p];
    float4 acc = bilinear_sum(c, f4);
    reinterpret_cast<float4*>(out)[tid] = acc;
}

extern "C" void kernel_launch(void* const* d_in, const int* in_sizes, int n_in,
                              void* d_out, int out_size, void* d_ws, size_t ws_size,
                              hipStream_t stream) {
    const float* inp = (const float*)d_in[0];
    const float* p0 = (const float*)d_in[1];
    const float* p1 = (const float*)d_in[2];
    const float* p2 = (const float*)d_in[3];
    float* out = (float*)d_out;

    transpose_kernel<<<(3 * PLANE_ELEMS) / 256, 256, 0, stream>>>(p0, p1, p2);

    const size_t coords_bytes = (size_t)NBINS * BIN_CAP * sizeof(float4); // 48 MB
    const size_t ids_bytes    = (size_t)NBINS * BIN_CAP * sizeof(int);    // 12 MB
    const size_t need = coords_bytes + ids_bytes + NBINS * sizeof(int);

    if (ws_size >= need) {
        float4* s_coords = (float4*)d_ws;
        int* s_ids = (int*)((char*)d_ws + coords_bytes);
        int* counts = (int*)((char*)d_ws + coords_bytes + ids_bytes);

        zero_counts_kernel<<<1, NBINS, 0, stream>>>(counts);
        scatter_kernel<<<NPTS / 8192, 1024, 0, stream>>>(inp, s_coords, s_ids, counts);
        dim3 grid(BLOCKS_PER_BIN, NBINS);
        sample_sorted_kernel<<<grid, 256, 0, stream>>>(s_coords, s_ids, counts, out);
    } else {
        sample_kernel<<<(NPTS * 8) / 256, 256, 0, stream>>>(inp, out);
    }
}